// Round 1
// baseline (2414.978 us; speedup 1.0000x reference)
//
#include <hip/hip_runtime.h>
#include <hip/hip_bf16.h>

// Problem constants
#define BB 4
#define SS 2048
#define DD 768
#define HH 12
#define DKV 64
#define NEGBIG (-1e30f)

// ---------------------------------------------------------------------------
// Projection GEMM: out[b,h,s,d] = X[row,:] @ W[:,col] + bias[col]
// X: [8192,768], W: [768,768], out: [B,H,S,64] with row=b*S+s, col=h*64+d
// 64x64 tile, BK=16, 256 threads, 4x4 micro-tile per thread.
// ---------------------------------------------------------------------------
__global__ __launch_bounds__(256) void proj_gemm(
    const float* __restrict__ X, const float* __restrict__ W,
    const float* __restrict__ bias, float* __restrict__ outp)
{
  const int K = DD, N = DD;
  const int row0 = blockIdx.x * 64;
  const int h    = blockIdx.y;      // col0 = h*64
  const int col0 = h << 6;
  const int tid = threadIdx.x;
  const int ty = tid >> 4, tx = tid & 15;

  __shared__ __align__(16) float As[16 * 64];  // [k][m] (transposed)
  __shared__ __align__(16) float Bs[16 * 64];  // [k][n]

  float acc[4][4] = {};
  for (int k0 = 0; k0 < K; k0 += 16) {
    {
      int r = tid >> 2, c = (tid & 3) << 2;
      float4 a4 = *(const float4*)&X[(size_t)(row0 + r) * K + k0 + c];
      As[(c + 0) * 64 + r] = a4.x; As[(c + 1) * 64 + r] = a4.y;
      As[(c + 2) * 64 + r] = a4.z; As[(c + 3) * 64 + r] = a4.w;
    }
    {
      int r = tid >> 4, c = (tid & 15) << 2;
      *(float4*)&Bs[r * 64 + c] = *(const float4*)&W[(size_t)(k0 + r) * N + col0 + c];
    }
    __syncthreads();
#pragma unroll
    for (int kk = 0; kk < 16; ++kk) {
      float4 a4 = *(float4*)&As[kk * 64 + ty * 4];
      float4 b4 = *(float4*)&Bs[kk * 64 + tx * 4];
      float a[4] = {a4.x, a4.y, a4.z, a4.w};
      float b[4] = {b4.x, b4.y, b4.z, b4.w};
#pragma unroll
      for (int i = 0; i < 4; i++)
#pragma unroll
        for (int j = 0; j < 4; j++) acc[i][j] += a[i] * b[j];
    }
    __syncthreads();
  }
  float4 bv4 = *(const float4*)&bias[col0 + tx * 4];
#pragma unroll
  for (int i = 0; i < 4; i++) {
    int row = row0 + ty * 4 + i;
    int b = row >> 11, s = row & (SS - 1);
    float4 o;
    o.x = acc[i][0] + bv4.x; o.y = acc[i][1] + bv4.y;
    o.z = acc[i][2] + bv4.z; o.w = acc[i][3] + bv4.w;
    *(float4*)&outp[(((size_t)b * HH + h) * SS + s) * DKV + tx * 4] = o;
  }
}

// ---------------------------------------------------------------------------
// Output projection: tmp[row,col] = ctx[row,:] @ Wo[:,col] + bo[col] + resid
// ---------------------------------------------------------------------------
__global__ __launch_bounds__(256) void outproj_gemm(
    const float* __restrict__ X, const float* __restrict__ W,
    const float* __restrict__ bias, const float* __restrict__ resid,
    float* __restrict__ outp)
{
  const int K = DD, N = DD;
  const int row0 = blockIdx.x * 64;
  const int col0 = blockIdx.y << 6;
  const int tid = threadIdx.x;
  const int ty = tid >> 4, tx = tid & 15;

  __shared__ __align__(16) float As[16 * 64];
  __shared__ __align__(16) float Bs[16 * 64];

  float acc[4][4] = {};
  for (int k0 = 0; k0 < K; k0 += 16) {
    {
      int r = tid >> 2, c = (tid & 3) << 2;
      float4 a4 = *(const float4*)&X[(size_t)(row0 + r) * K + k0 + c];
      As[(c + 0) * 64 + r] = a4.x; As[(c + 1) * 64 + r] = a4.y;
      As[(c + 2) * 64 + r] = a4.z; As[(c + 3) * 64 + r] = a4.w;
    }
    {
      int r = tid >> 4, c = (tid & 15) << 2;
      *(float4*)&Bs[r * 64 + c] = *(const float4*)&W[(size_t)(k0 + r) * N + col0 + c];
    }
    __syncthreads();
#pragma unroll
    for (int kk = 0; kk < 16; ++kk) {
      float4 a4 = *(float4*)&As[kk * 64 + ty * 4];
      float4 b4 = *(float4*)&Bs[kk * 64 + tx * 4];
      float a[4] = {a4.x, a4.y, a4.z, a4.w};
      float b[4] = {b4.x, b4.y, b4.z, b4.w};
#pragma unroll
      for (int i = 0; i < 4; i++)
#pragma unroll
        for (int j = 0; j < 4; j++) acc[i][j] += a[i] * b[j];
    }
    __syncthreads();
  }
  float4 bv4 = *(const float4*)&bias[col0 + tx * 4];
#pragma unroll
  for (int i = 0; i < 4; i++) {
    int row = row0 + ty * 4 + i;
    float4 r4 = *(const float4*)&resid[(size_t)row * DD + col0 + tx * 4];
    float4 o;
    o.x = acc[i][0] + bv4.x + r4.x; o.y = acc[i][1] + bv4.y + r4.y;
    o.z = acc[i][2] + bv4.z + r4.z; o.w = acc[i][3] + bv4.w + r4.w;
    *(float4*)&outp[(size_t)row * DD + col0 + tx * 4] = o;
  }
}

// ---------------------------------------------------------------------------
// Attention: one block per (b, h, 64-query tile). Two passes over K chunks:
// pass1 computes online (m,l) per query row; pass2 recomputes scores, writes
// normalized attn to d_out, and accumulates context = P @ V in registers.
// ---------------------------------------------------------------------------
__global__ __launch_bounds__(256) void attn_kernel(
    const float* __restrict__ qh, const float* __restrict__ kh,
    const float* __restrict__ vh, const int* __restrict__ pad,
    float* __restrict__ attn, float* __restrict__ ctx)
{
  const int qt = blockIdx.x, h = blockIdx.y, b = blockIdx.z;
  const int tid = threadIdx.x;
  const int ty = tid >> 4, tx = tid & 15;

  const float* qbase = qh + (((size_t)b * HH + h) * SS + qt * 64) * DKV;
  const float* kbase = kh + (((size_t)b * HH + h) * SS) * DKV;
  const float* vbase = vh + (((size_t)b * HH + h) * SS) * DKV;

  __shared__ __align__(16) float QsT[64 * 64];   // [dk][q]
  __shared__ __align__(16) float KV[64 * 64];    // K^T: [dk][k]  /  V: [k][dv]
  __shared__ __align__(16) float Sc[64 * 68];    // [q][k] padded
  __shared__ float red[64 * 4];
  __shared__ float mrow[64], lrow[64], mnew_s[64];

  // load Q tile transposed
  {
    int r = tid >> 2, cb = (tid & 3) << 4;
    const float* qr = qbase + (size_t)r * DKV;
#pragma unroll
    for (int q = 0; q < 4; q++) {
      float4 v = *(const float4*)(qr + cb + q * 4);
      QsT[(cb + q * 4 + 0) * 64 + r] = v.x; QsT[(cb + q * 4 + 1) * 64 + r] = v.y;
      QsT[(cb + q * 4 + 2) * 64 + r] = v.z; QsT[(cb + q * 4 + 3) * 64 + r] = v.w;
    }
  }
  if (tid < 64) { mrow[tid] = NEGBIG; lrow[tid] = 0.f; }
  __syncthreads();

  // ---------------- pass 1: online max/sum ----------------
  for (int kc = 0; kc < SS / 64; ++kc) {
    int kc0 = kc << 6;
    {
      int r = tid >> 2, cb = (tid & 3) << 4;
      const float* krow = kbase + (size_t)(kc0 + r) * DKV;
#pragma unroll
      for (int q = 0; q < 4; q++) {
        float4 v = *(const float4*)(krow + cb + q * 4);
        KV[(cb + q * 4 + 0) * 64 + r] = v.x; KV[(cb + q * 4 + 1) * 64 + r] = v.y;
        KV[(cb + q * 4 + 2) * 64 + r] = v.z; KV[(cb + q * 4 + 3) * 64 + r] = v.w;
      }
    }
    __syncthreads();
    float s[4][4] = {};
#pragma unroll 16
    for (int kk = 0; kk < 64; ++kk) {
      float4 a4 = *(float4*)&QsT[kk * 64 + ty * 4];
      float4 b4 = *(float4*)&KV[kk * 64 + tx * 4];
      float a[4] = {a4.x, a4.y, a4.z, a4.w};
      float bb[4] = {b4.x, b4.y, b4.z, b4.w};
#pragma unroll
      for (int i = 0; i < 4; i++)
#pragma unroll
        for (int j = 0; j < 4; j++) s[i][j] += a[i] * bb[j];
    }
#pragma unroll
    for (int i = 0; i < 4; i++) {
      int qglob = qt * 64 + ty * 4 + i;
      const int4 pm = *(const int4*)&pad[((size_t)b * SS + qglob) * SS + kc0 + tx * 4];
      float4 o;
      o.x = pm.x ? -1e9f : s[i][0] * 0.125f;
      o.y = pm.y ? -1e9f : s[i][1] * 0.125f;
      o.z = pm.z ? -1e9f : s[i][2] * 0.125f;
      o.w = pm.w ? -1e9f : s[i][3] * 0.125f;
      *(float4*)&Sc[(ty * 4 + i) * 68 + tx * 4] = o;
    }
    __syncthreads();
    {
      int r = tid >> 2, seg = tid & 3;
      const float* srow = &Sc[r * 68 + seg * 16];
      float mx = NEGBIG;
#pragma unroll
      for (int t = 0; t < 16; t++) mx = fmaxf(mx, srow[t]);
      red[r * 4 + seg] = mx;
      __syncthreads();
      if (seg == 0) {
        float cm = fmaxf(fmaxf(red[r * 4], red[r * 4 + 1]),
                         fmaxf(red[r * 4 + 2], red[r * 4 + 3]));
        mnew_s[r] = fmaxf(mrow[r], cm);
      }
      __syncthreads();
      float mn = mnew_s[r];
      float se = 0.f;
#pragma unroll
      for (int t = 0; t < 16; t++) se += __expf(srow[t] - mn);
      red[r * 4 + seg] = se;
      __syncthreads();
      if (seg == 0) {
        float ssum = red[r * 4] + red[r * 4 + 1] + red[r * 4 + 2] + red[r * 4 + 3];
        lrow[r] = lrow[r] * __expf(mrow[r] - mn) + ssum;
        mrow[r] = mn;
      }
    }
    __syncthreads();
  }

  // per-thread final (m, 1/l) for its 4 rows
  float mloc[4], linv[4];
#pragma unroll
  for (int i = 0; i < 4; i++) {
    mloc[i] = mrow[ty * 4 + i];
    linv[i] = 1.f / lrow[ty * 4 + i];
  }
  float cacc[4][4] = {};

  // ---------------- pass 2: write attn + accumulate context ----------------
  for (int kc = 0; kc < SS / 64; ++kc) {
    int kc0 = kc << 6;
    {
      int r = tid >> 2, cb = (tid & 3) << 4;
      const float* krow = kbase + (size_t)(kc0 + r) * DKV;
#pragma unroll
      for (int q = 0; q < 4; q++) {
        float4 v = *(const float4*)(krow + cb + q * 4);
        KV[(cb + q * 4 + 0) * 64 + r] = v.x; KV[(cb + q * 4 + 1) * 64 + r] = v.y;
        KV[(cb + q * 4 + 2) * 64 + r] = v.z; KV[(cb + q * 4 + 3) * 64 + r] = v.w;
      }
    }
    __syncthreads();
    float s[4][4] = {};
#pragma unroll 16
    for (int kk = 0; kk < 64; ++kk) {
      float4 a4 = *(float4*)&QsT[kk * 64 + ty * 4];
      float4 b4 = *(float4*)&KV[kk * 64 + tx * 4];
      float a[4] = {a4.x, a4.y, a4.z, a4.w};
      float bb[4] = {b4.x, b4.y, b4.z, b4.w};
#pragma unroll
      for (int i = 0; i < 4; i++)
#pragma unroll
        for (int j = 0; j < 4; j++) s[i][j] += a[i] * bb[j];
    }
#pragma unroll
    for (int i = 0; i < 4; i++) {
      int qglob = qt * 64 + ty * 4 + i;
      const int4 pm = *(const int4*)&pad[((size_t)b * SS + qglob) * SS + kc0 + tx * 4];
      float sv0 = pm.x ? -1e9f : s[i][0] * 0.125f;
      float sv1 = pm.y ? -1e9f : s[i][1] * 0.125f;
      float sv2 = pm.z ? -1e9f : s[i][2] * 0.125f;
      float sv3 = pm.w ? -1e9f : s[i][3] * 0.125f;
      float4 o;
      o.x = __expf(sv0 - mloc[i]) * linv[i];
      o.y = __expf(sv1 - mloc[i]) * linv[i];
      o.z = __expf(sv2 - mloc[i]) * linv[i];
      o.w = __expf(sv3 - mloc[i]) * linv[i];
      *(float4*)&attn[(((size_t)b * HH + h) * SS + qglob) * SS + kc0 + tx * 4] = o;
      *(float4*)&Sc[(ty * 4 + i) * 68 + tx * 4] = o;
    }
    __syncthreads();
    // load V chunk (natural layout) into KV
    {
      int r = tid >> 2, cb = (tid & 3) << 4;
      const float* vrow = vbase + (size_t)(kc0 + r) * DKV;
#pragma unroll
      for (int q = 0; q < 4; q++)
        *(float4*)&KV[r * 64 + cb + q * 4] = *(const float4*)(vrow + cb + q * 4);
    }
    __syncthreads();
#pragma unroll 8
    for (int kk = 0; kk < 64; ++kk) {
      float a0 = Sc[(ty * 4 + 0) * 68 + kk];
      float a1 = Sc[(ty * 4 + 1) * 68 + kk];
      float a2 = Sc[(ty * 4 + 2) * 68 + kk];
      float a3 = Sc[(ty * 4 + 3) * 68 + kk];
      float4 b4 = *(float4*)&KV[kk * 64 + tx * 4];
      float bb[4] = {b4.x, b4.y, b4.z, b4.w};
#pragma unroll
      for (int j = 0; j < 4; j++) {
        cacc[0][j] += a0 * bb[j];
        cacc[1][j] += a1 * bb[j];
        cacc[2][j] += a2 * bb[j];
        cacc[3][j] += a3 * bb[j];
      }
    }
    __syncthreads();
  }
  // write context in [B,S,H*DV] layout
#pragma unroll
  for (int i = 0; i < 4; i++) {
    int row = qt * 64 + ty * 4 + i;
    float4 o = {cacc[i][0], cacc[i][1], cacc[i][2], cacc[i][3]};
    *(float4*)&ctx[((size_t)b * SS + row) * DD + h * DKV + tx * 4] = o;
  }
}

// ---------------------------------------------------------------------------
// LayerNorm over last dim (768), one block (256 thr) per row.
// ---------------------------------------------------------------------------
__global__ __launch_bounds__(256) void ln_kernel(
    const float* __restrict__ x, const float* __restrict__ gam,
    const float* __restrict__ bet, float* __restrict__ out)
{
  const int row = blockIdx.x;
  const int tid = threadIdx.x;
  const float* xr = x + (size_t)row * DD;
  float v0 = xr[tid], v1 = xr[tid + 256], v2 = xr[tid + 512];
  float s1 = v0 + v1 + v2;
  float s2 = v0 * v0 + v1 * v1 + v2 * v2;
  __shared__ float r1[256], r2[256];
  r1[tid] = s1; r2[tid] = s2;
  __syncthreads();
  for (int off = 128; off > 0; off >>= 1) {
    if (tid < off) { r1[tid] += r1[tid + off]; r2[tid] += r2[tid + off]; }
    __syncthreads();
  }
  __shared__ float mu_s, rs_s;
  if (tid == 0) {
    float mu = r1[0] * (1.f / 768.f);
    float var = r2[0] * (1.f / 768.f) - mu * mu;
    mu_s = mu; rs_s = rsqrtf(var + 1e-5f);
  }
  __syncthreads();
  float mu = mu_s, rs = rs_s;
  float* orow = out + (size_t)row * DD;
  orow[tid]       = (v0 - mu) * rs * gam[tid]       + bet[tid];
  orow[tid + 256] = (v1 - mu) * rs * gam[tid + 256] + bet[tid + 256];
  orow[tid + 512] = (v2 - mu) * rs * gam[tid + 512] + bet[tid + 512];
}

// ---------------------------------------------------------------------------
extern "C" void kernel_launch(void* const* d_in, const int* in_sizes, int n_in,
                              void* d_out, int out_size, void* d_ws, size_t ws_size,
                              hipStream_t stream) {
  const float* Q   = (const float*)d_in[0];
  const float* K   = (const float*)d_in[1];
  const float* V   = (const float*)d_in[2];
  const int*   pad = (const int*)d_in[3];
  const float* Wq  = (const float*)d_in[4];
  const float* bq  = (const float*)d_in[5];
  const float* Wk  = (const float*)d_in[6];
  const float* bk  = (const float*)d_in[7];
  const float* Wv  = (const float*)d_in[8];
  const float* bv  = (const float*)d_in[9];
  const float* Wo  = (const float*)d_in[10];
  const float* bo  = (const float*)d_in[11];
  const float* lng = (const float*)d_in[12];
  const float* lnb = (const float*)d_in[13];

  float* out  = (float*)d_out;                       // [B,S,D]
  float* attn = out + (size_t)BB * SS * DD;          // [B,H,S,S]

  const size_t NQ = (size_t)BB * SS * DD;            // 6291456
  float* ws  = (float*)d_ws;
  float* qh  = ws;                                    // [B,H,S,64]
  float* khp = ws + NQ;
  float* vhp = ws + 2 * NQ;
  float* ctx = ws + 3 * NQ;                           // [B,S,768]
  float* tmp = qh;                                    // reuse (qh dead after attn)

  dim3 gproj(SS * BB / 64, DD / 64);                  // (128, 12)
  proj_gemm<<<gproj, 256, 0, stream>>>(Q, Wq, bq, qh);
  proj_gemm<<<gproj, 256, 0, stream>>>(K, Wk, bk, khp);
  proj_gemm<<<gproj, 256, 0, stream>>>(V, Wv, bv, vhp);

  dim3 gattn(SS / 64, HH, BB);                        // (32, 12, 4)
  attn_kernel<<<gattn, 256, 0, stream>>>(qh, khp, vhp, pad, attn, ctx);

  outproj_gemm<<<gproj, 256, 0, stream>>>(ctx, Wo, bo, Q, tmp);

  ln_kernel<<<BB * SS, 256, 0, stream>>>(tmp, lng, lnb, out);
}